// Round 9
// baseline (601.926 us; speedup 1.0000x reference)
//
#include <hip/hip_runtime.h>

#define N_NODES 40000
#define N_EDGES 640000
#define D 128                  // D_IN == D_OUT == 128
#define GEMM_ROWS 32           // rows per gemm block (40000/32 = 1250 exact)
#define NBUCK 1024             // coarse dst-buckets
#define NPB   40               // nodes per bucket; 1000*40 = 40000 exact, buckets 1000..1023 empty
#define HB    64               // histogram/scatter blocks
#define EPHB  (N_EDGES / HB)   // 10000 edges per block (exact)

typedef float f32x4 __attribute__((ext_vector_type(4)));
typedef unsigned long long u64;

// ---------------------------------------------------------------------------
// Workspace layout (16B-aligned):
//   y      : N_NODES*D f32   (x @ W)
//   deg    : N_NODES int     (in-degree)        } zeroed together
//   ccnt   : NBUCK int       (bucket counts)    }
//   cbase  : NBUCK+4 int     (bucket offsets, exclusive scan)
//   ccur   : NBUCK int       (bucket fill cursors)
//   pairs  : N_EDGES u64     (lo16=src, [16:23]=dstloc, hi32=bits(ew)), bucket-grouped
// ---------------------------------------------------------------------------

// K1: per-bucket histogram (LDS) + per-node degree atomics (fire-and-forget).
__global__ __launch_bounds__(256) void histdeg_kernel(const int* __restrict__ dst,
                                                      int* __restrict__ deg,
                                                      int* __restrict__ ccnt) {
    __shared__ int hist[NBUCK];
    const int tid = threadIdx.x;
    for (int i = tid; i < NBUCK; i += 256) hist[i] = 0;
    __syncthreads();
    const int base = blockIdx.x * EPHB;
    for (int i = tid; i < EPHB; i += 256) {
        int d = dst[base + i];
        atomicAdd(&deg[d], 1);          // no return use -> no-wait atomic
        atomicAdd(&hist[d / NPB], 1);   // LDS atomic
    }
    __syncthreads();
    for (int i = tid; i < NBUCK; i += 256) {
        int h = hist[i];
        if (h) atomicAdd(&ccnt[i], h);
    }
}

// K2: exclusive scan of ccnt[1024] -> cbase; init ccur = cbase.
__global__ __launch_bounds__(1024) void scan_kernel(const int* __restrict__ ccnt,
                                                    int* __restrict__ cbase,
                                                    int* __restrict__ ccur) {
    __shared__ int s[NBUCK];
    int t = threadIdx.x;
    int v = ccnt[t];
    s[t] = v;
    __syncthreads();
#pragma unroll
    for (int off = 1; off < NBUCK; off <<= 1) {
        int u = (t >= off) ? s[t - off] : 0;
        __syncthreads();
        s[t] += u;
        __syncthreads();
    }
    int excl = s[t] - v;
    cbase[t] = excl;
    ccur[t]  = excl;
    if (t == NBUCK - 1) cbase[NBUCK] = excl + v;   // == N_EDGES
}

// K3: bucket-grouped edge scatter with per-block dense reservations.
// Each block: LDS hist -> one atomicAdd per bucket reserves a contiguous
// range -> edges written densely into the range (single-writer lines).
__global__ __launch_bounds__(256) void scatterA_kernel(const int* __restrict__ src,
                                                       const int* __restrict__ dst,
                                                       const float* __restrict__ ew,
                                                       int* __restrict__ ccur,
                                                       u64* __restrict__ pairs) {
    __shared__ int hbase[NBUCK];   // count, then block's reserved base
    __shared__ int lcur[NBUCK];    // local fill cursor
    const int tid = threadIdx.x;
    for (int i = tid; i < NBUCK; i += 256) hbase[i] = 0;
    __syncthreads();
    const int base = blockIdx.x * EPHB;
    for (int i = tid; i < EPHB; i += 256)
        atomicAdd(&hbase[dst[base + i] / NPB], 1);
    __syncthreads();
    for (int i = tid; i < NBUCK; i += 256) {
        int h = hbase[i];
        hbase[i] = h ? atomicAdd(&ccur[i], h) : 0;
        lcur[i] = 0;
    }
    __syncthreads();
    for (int i = tid; i < EPHB; i += 256) {
        int d = dst[base + i];
        int bk = d / NPB;
        int loc = d - bk * NPB;                       // < 40
        int pos = hbase[bk] + atomicAdd(&lcur[bk], 1);
        u64 pk = (u64)(unsigned int)(src[base + i] | (loc << 16))
               | ((u64)__float_as_uint(ew[base + i]) << 32);
        pairs[pos] = pk;                              // normal store: L2-absorbed
    }
}

// K4: y = x @ W (fp32 vector GEMM; no fp32 MFMA on CDNA4).
// Block = 256 threads computes a 32-row x 128-col tile; W (64KB) + x tile
// (16KB) staged in LDS (REQUIRED: global-W version is latency-bound, R6).
__global__ __launch_bounds__(256) void gemm_xw_kernel(const float* __restrict__ x,
                                                      const float* __restrict__ W,
                                                      float* __restrict__ y) {
    __shared__ float Ws[D * D];             // 64 KB, [k][c] row-major
    __shared__ float xs[GEMM_ROWS * D];     // 16 KB
    const int tid = threadIdx.x;
    const int rowbase = blockIdx.x * GEMM_ROWS;

    float4* Ws4 = reinterpret_cast<float4*>(Ws);
    const float4* W4 = reinterpret_cast<const float4*>(W);
#pragma unroll
    for (int i = 0; i < 16; ++i)                  // 4096 float4 / 256 thr
        Ws4[tid + i * 256] = W4[tid + i * 256];

    float4* xs4 = reinterpret_cast<float4*>(xs);
    const float4* x4 = reinterpret_cast<const float4*>(x) + rowbase * (D / 4);
#pragma unroll
    for (int i = 0; i < GEMM_ROWS * (D / 4) / 256; ++i)   // 1024/256 = 4
        xs4[tid + i * 256] = x4[tid + i * 256];
    __syncthreads();

    const int lane = tid & 31;
    const int rp   = tid >> 5;                    // 0..7 -> rows 4rp..4rp+3
    const float* xr0 = xs + (rp * 4 + 0) * D;
    const float* xr1 = xs + (rp * 4 + 1) * D;
    const float* xr2 = xs + (rp * 4 + 2) * D;
    const float* xr3 = xs + (rp * 4 + 3) * D;

    float4 a0 = {0.f,0.f,0.f,0.f}, a1 = a0, a2 = a0, a3 = a0;
#pragma unroll 4
    for (int k = 0; k < D; ++k) {
        float4 wv = Ws4[k * (D / 4) + lane];      // ds_read_b128
        float x0 = xr0[k], x1 = xr1[k], x2 = xr2[k], x3 = xr3[k];
        a0.x += x0*wv.x; a0.y += x0*wv.y; a0.z += x0*wv.z; a0.w += x0*wv.w;
        a1.x += x1*wv.x; a1.y += x1*wv.y; a1.z += x1*wv.z; a1.w += x1*wv.w;
        a2.x += x2*wv.x; a2.y += x2*wv.y; a2.z += x2*wv.z; a2.w += x2*wv.w;
        a3.x += x3*wv.x; a3.y += x3*wv.y; a3.z += x3*wv.z; a3.w += x3*wv.w;
    }

    float4* y4 = reinterpret_cast<float4*>(y);
    int r0 = rowbase + rp * 4;
    y4[(r0 + 0) * (D / 4) + lane] = a0;
    y4[(r0 + 1) * (D / 4) + lane] = a1;
    y4[(r0 + 2) * (D / 4) + lane] = a2;
    y4[(r0 + 3) * (D / 4) + lane] = a3;
}

// K5: per-bucket accumulate. One block per bucket; 40x128 f32 LDS accumulator.
// 8 lane-groups x 2-edge ILP stream the bucket's contiguous edge slice; each
// lane owns columns {part, part+32, part+64, part+96} (conflict-free ds_add).
// Final: out[node] = acc[row]*invdeg(node) + b, written once, densely.
__global__ __launch_bounds__(256) void passB_kernel(const int* __restrict__ cbase,
                                                    const u64* __restrict__ pairs,
                                                    const int* __restrict__ deg,
                                                    const float* __restrict__ y,
                                                    const float* __restrict__ b,
                                                    float* __restrict__ out) {
    __shared__ float acc[NPB * D];   // 20 KB
    const int bkt = blockIdx.x;
    const int node0 = bkt * NPB;
    if (node0 >= N_NODES) return;    // empty tail buckets (uniform per block)
    const int tid  = threadIdx.x;
    const int part = tid & 31;
    const int g    = tid >> 5;       // 8 groups

    for (int i = tid; i < NPB * D; i += 256) acc[i] = 0.f;
    __syncthreads();

    const int eb = cbase[bkt], ee = cbase[bkt + 1];
    for (int e0 = eb + g * 2; e0 < ee; e0 += 16) {
        u64 p0 = __builtin_nontemporal_load(&pairs[e0]);
        int  has1 = (e0 + 1 < ee);
        u64 p1 = has1 ? __builtin_nontemporal_load(&pairs[e0 + 1]) : 0;

        int   s0 = (int)(p0 & 0xffffu);
        int   l0 = (int)((p0 >> 16) & 0xffu);
        float w0 = __uint_as_float((unsigned int)(p0 >> 32));
        const float* yr0 = y + s0 * D + part;
        float v00 = yr0[0], v01 = yr0[32], v02 = yr0[64], v03 = yr0[96];

        int   s1 = (int)(p1 & 0xffffu);
        int   l1 = (int)((p1 >> 16) & 0xffu);
        float w1 = __uint_as_float((unsigned int)(p1 >> 32));
        const float* yr1 = y + s1 * D + part;
        float v10 = 0.f, v11 = 0.f, v12 = 0.f, v13 = 0.f;
        if (has1) { v10 = yr1[0]; v11 = yr1[32]; v12 = yr1[64]; v13 = yr1[96]; }

        float* a0 = acc + l0 * D + part;
        atomicAdd(a0 +  0, w0 * v00);
        atomicAdd(a0 + 32, w0 * v01);
        atomicAdd(a0 + 64, w0 * v02);
        atomicAdd(a0 + 96, w0 * v03);
        if (has1) {
            float* a1 = acc + l1 * D + part;
            atomicAdd(a1 +  0, w1 * v10);
            atomicAdd(a1 + 32, w1 * v11);
            atomicAdd(a1 + 64, w1 * v12);
            atomicAdd(a1 + 96, w1 * v13);
        }
    }
    __syncthreads();

    const float4* b4 = reinterpret_cast<const float4*>(b);
    f32x4* out4 = reinterpret_cast<f32x4*>(out);
    int nrows = N_NODES - node0; if (nrows > NPB) nrows = NPB;
    for (int r = g; r < nrows; r += 8) {
        int node = node0 + r;
        int dg = deg[node];
        float inv = (dg > 0) ? (1.0f / (float)dg) : 0.0f;
        float4 bv = b4[part];
        const float* ar = acc + r * D + part * 4;
        f32x4 o;
        o.x = ar[0] * inv + bv.x;
        o.y = ar[1] * inv + bv.y;
        o.z = ar[2] * inv + bv.z;
        o.w = ar[3] * inv + bv.w;
        __builtin_nontemporal_store(o, out4 + node * (D / 4) + part);
    }
}

// ---------------------------------------------------------------------------
extern "C" void kernel_launch(void* const* d_in, const int* in_sizes, int n_in,
                              void* d_out, int out_size, void* d_ws, size_t ws_size,
                              hipStream_t stream) {
    const float* x   = (const float*)d_in[0];
    const int*   src = (const int*)d_in[1];
    const int*   dst = (const int*)d_in[2];
    const float* ew  = (const float*)d_in[3];
    const float* W   = (const float*)d_in[4];
    const float* b   = (const float*)d_in[5];
    float* out = (float*)d_out;

    char* ws = (char*)d_ws;
    float* y     = (float*)ws;                        ws += (size_t)N_NODES * D * 4;
    int*   deg   = (int*)ws;                          ws += (size_t)N_NODES * 4;
    int*   ccnt  = (int*)ws;                          ws += (size_t)NBUCK * 4;
    int*   cbase = (int*)ws;                          ws += (size_t)(NBUCK + 4) * 4;
    int*   ccur  = (int*)ws;                          ws += (size_t)NBUCK * 4;
    u64*   pairs = (u64*)ws;

    // zero deg + ccnt in one contiguous async memset (graph-capturable)
    hipMemsetAsync(deg, 0, (size_t)(N_NODES + NBUCK) * 4, stream);

    histdeg_kernel<<<HB, 256, 0, stream>>>(dst, deg, ccnt);
    scan_kernel<<<1, NBUCK, 0, stream>>>(ccnt, cbase, ccur);
    scatterA_kernel<<<HB, 256, 0, stream>>>(src, dst, ew, ccur, pairs);
    gemm_xw_kernel<<<N_NODES / GEMM_ROWS, 256, 0, stream>>>(x, W, y);
    passB_kernel<<<NBUCK, 256, 0, stream>>>(cbase, pairs, deg, y, b, out);
}

// Round 10
// 582.637 us; speedup vs baseline: 1.0331x; 1.0331x over previous
//
#include <hip/hip_runtime.h>

#define N_NODES 40000
#define N_EDGES 640000
#define D 128                  // D_IN == D_OUT == 128
#define GEMM_ROWS 32           // rows per gemm block (40000/32 = 1250 exact)
#define NBUCK 1024             // coarse dst-buckets
#define NPB   40               // nodes per bucket; 1000*40 = 40000 exact
#define HB    64               // histogram/scatter blocks
#define EPHB  (N_EDGES / HB)   // 10000 edges per block (exact)

typedef float f32x4 __attribute__((ext_vector_type(4)));
typedef unsigned long long u64;

// ---------------------------------------------------------------------------
// Workspace layout (16B-aligned):
//   y      : N_NODES*D f32   (x @ W)
//   ccnt   : NBUCK int       (bucket counts)  <- only thing memset to 0
//   cbase  : NBUCK+4 int     (bucket offsets, exclusive scan)
//   ccur   : NBUCK int       (bucket fill cursors)
//   pairs  : N_EDGES u64     (lo16=src, [16:23]=dstloc, hi32=bits(ew)), bucket-grouped
// Degree is recovered inside passB (every edge of node v is in bucket v/NPB).
// ---------------------------------------------------------------------------

// K1: per-bucket histogram (LDS) only.
__global__ __launch_bounds__(256) void hist_kernel(const int* __restrict__ dst,
                                                   int* __restrict__ ccnt) {
    __shared__ int hist[NBUCK];
    const int tid = threadIdx.x;
    for (int i = tid; i < NBUCK; i += 256) hist[i] = 0;
    __syncthreads();
    const int base = blockIdx.x * EPHB;
    for (int i = tid; i < EPHB; i += 256)
        atomicAdd(&hist[dst[base + i] / NPB], 1);   // LDS atomic
    __syncthreads();
    for (int i = tid; i < NBUCK; i += 256) {
        int h = hist[i];
        if (h) atomicAdd(&ccnt[i], h);
    }
}

// K2: exclusive scan of ccnt[1024] -> cbase; init ccur = cbase.
__global__ __launch_bounds__(1024) void scan_kernel(const int* __restrict__ ccnt,
                                                    int* __restrict__ cbase,
                                                    int* __restrict__ ccur) {
    __shared__ int s[NBUCK];
    int t = threadIdx.x;
    int v = ccnt[t];
    s[t] = v;
    __syncthreads();
#pragma unroll
    for (int off = 1; off < NBUCK; off <<= 1) {
        int u = (t >= off) ? s[t - off] : 0;
        __syncthreads();
        s[t] += u;
        __syncthreads();
    }
    int excl = s[t] - v;
    cbase[t] = excl;
    ccur[t]  = excl;
    if (t == NBUCK - 1) cbase[NBUCK] = excl + v;   // == N_EDGES
}

// K3: bucket-grouped edge scatter with per-block dense reservations.
__global__ __launch_bounds__(256) void scatterA_kernel(const int* __restrict__ src,
                                                       const int* __restrict__ dst,
                                                       const float* __restrict__ ew,
                                                       int* __restrict__ ccur,
                                                       u64* __restrict__ pairs) {
    __shared__ int hbase[NBUCK];   // count, then block's reserved base
    __shared__ int lcur[NBUCK];    // local fill cursor
    const int tid = threadIdx.x;
    for (int i = tid; i < NBUCK; i += 256) hbase[i] = 0;
    __syncthreads();
    const int base = blockIdx.x * EPHB;
    for (int i = tid; i < EPHB; i += 256)
        atomicAdd(&hbase[dst[base + i] / NPB], 1);
    __syncthreads();
    for (int i = tid; i < NBUCK; i += 256) {
        int h = hbase[i];
        hbase[i] = h ? atomicAdd(&ccur[i], h) : 0;
        lcur[i] = 0;
    }
    __syncthreads();
    for (int i = tid; i < EPHB; i += 256) {
        int d = dst[base + i];
        int bk = d / NPB;
        int loc = d - bk * NPB;                       // < 40
        int pos = hbase[bk] + atomicAdd(&lcur[bk], 1);
        u64 pk = (u64)(unsigned int)(src[base + i] | (loc << 16))
               | ((u64)__float_as_uint(ew[base + i]) << 32);
        pairs[pos] = pk;                              // dense, L2-absorbed
    }
}

// K4: y = x @ W (fp32 vector GEMM; no fp32 MFMA on CDNA4).
// Block = 256 threads computes a 32-row x 128-col tile; W (64KB) + x tile
// (16KB) staged in LDS (REQUIRED: global-W version is latency-bound, R6).
__global__ __launch_bounds__(256) void gemm_xw_kernel(const float* __restrict__ x,
                                                      const float* __restrict__ W,
                                                      float* __restrict__ y) {
    __shared__ float Ws[D * D];             // 64 KB, [k][c] row-major
    __shared__ float xs[GEMM_ROWS * D];     // 16 KB
    const int tid = threadIdx.x;
    const int rowbase = blockIdx.x * GEMM_ROWS;

    float4* Ws4 = reinterpret_cast<float4*>(Ws);
    const float4* W4 = reinterpret_cast<const float4*>(W);
#pragma unroll
    for (int i = 0; i < 16; ++i)                  // 4096 float4 / 256 thr
        Ws4[tid + i * 256] = W4[tid + i * 256];

    float4* xs4 = reinterpret_cast<float4*>(xs);
    const float4* x4 = reinterpret_cast<const float4*>(x) + rowbase * (D / 4);
#pragma unroll
    for (int i = 0; i < GEMM_ROWS * (D / 4) / 256; ++i)   // 1024/256 = 4
        xs4[tid + i * 256] = x4[tid + i * 256];
    __syncthreads();

    const int lane = tid & 31;
    const int rp   = tid >> 5;                    // 0..7 -> rows 4rp..4rp+3
    const float* xr0 = xs + (rp * 4 + 0) * D;
    const float* xr1 = xs + (rp * 4 + 1) * D;
    const float* xr2 = xs + (rp * 4 + 2) * D;
    const float* xr3 = xs + (rp * 4 + 3) * D;

    float4 a0 = {0.f,0.f,0.f,0.f}, a1 = a0, a2 = a0, a3 = a0;
#pragma unroll 4
    for (int k = 0; k < D; ++k) {
        float4 wv = Ws4[k * (D / 4) + lane];      // ds_read_b128
        float x0 = xr0[k], x1 = xr1[k], x2 = xr2[k], x3 = xr3[k];
        a0.x += x0*wv.x; a0.y += x0*wv.y; a0.z += x0*wv.z; a0.w += x0*wv.w;
        a1.x += x1*wv.x; a1.y += x1*wv.y; a1.z += x1*wv.z; a1.w += x1*wv.w;
        a2.x += x2*wv.x; a2.y += x2*wv.y; a2.z += x2*wv.z; a2.w += x2*wv.w;
        a3.x += x3*wv.x; a3.y += x3*wv.y; a3.z += x3*wv.z; a3.w += x3*wv.w;
    }

    float4* y4 = reinterpret_cast<float4*>(y);
    int r0 = rowbase + rp * 4;
    y4[(r0 + 0) * (D / 4) + lane] = a0;
    y4[(r0 + 1) * (D / 4) + lane] = a1;
    y4[(r0 + 2) * (D / 4) + lane] = a2;
    y4[(r0 + 3) * (D / 4) + lane] = a3;
}

// K5: per-bucket accumulate. One block (512 thr, 16 groups) per bucket;
// 40x128 f32 LDS accumulator. Each group takes 4 edges per iteration:
// 4 pair loads then 16 independent y loads in flight, then 16 conflict-free
// ds_add_f32 (stride-32 column layout: 2 lanes/bank per wave = free).
// Degree counted in LDS (all edges of a node are in its bucket).
// Final: out[node] = acc[row]/deg + b, written once, densely.
__global__ __launch_bounds__(512) void passB_kernel(const int* __restrict__ cbase,
                                                    const u64* __restrict__ pairs,
                                                    const float* __restrict__ y,
                                                    const float* __restrict__ b,
                                                    float* __restrict__ out) {
    __shared__ float acc[NPB * D];   // 20 KB
    __shared__ int   cnt[NPB];
    const int bkt = blockIdx.x;
    const int node0 = bkt * NPB;
    if (node0 >= N_NODES) return;    // uniform per block
    const int tid  = threadIdx.x;
    const int part = tid & 31;
    const int g    = tid >> 5;       // 0..15

    for (int i = tid; i < NPB * D; i += 512) acc[i] = 0.f;
    if (tid < NPB) cnt[tid] = 0;
    __syncthreads();

    const int eb = cbase[bkt], ee = cbase[bkt + 1];
    for (int e0 = eb + g * 4; e0 < ee; e0 += 64) {
        int n = ee - e0; if (n > 4) n = 4;
        u64 p0 = pairs[e0];
        u64 p1 = (n > 1) ? pairs[e0 + 1] : 0;
        u64 p2 = (n > 2) ? pairs[e0 + 2] : 0;
        u64 p3 = (n > 3) ? pairs[e0 + 3] : 0;

        int   s0 = (int)(p0 & 0xffffu), l0 = (int)((p0 >> 16) & 0xffu);
        int   s1 = (int)(p1 & 0xffffu), l1 = (int)((p1 >> 16) & 0xffu);
        int   s2 = (int)(p2 & 0xffffu), l2 = (int)((p2 >> 16) & 0xffu);
        int   s3 = (int)(p3 & 0xffffu), l3 = (int)((p3 >> 16) & 0xffu);
        float w0 = __uint_as_float((unsigned int)(p0 >> 32));
        float w1 = (n > 1) ? __uint_as_float((unsigned int)(p1 >> 32)) : 0.f;
        float w2 = (n > 2) ? __uint_as_float((unsigned int)(p2 >> 32)) : 0.f;
        float w3 = (n > 3) ? __uint_as_float((unsigned int)(p3 >> 32)) : 0.f;

        // 16 independent loads in flight
        const float* yr0 = y + s0 * D + part;
        const float* yr1 = y + s1 * D + part;
        const float* yr2 = y + s2 * D + part;
        const float* yr3 = y + s3 * D + part;
        float v00 = yr0[0], v01 = yr0[32], v02 = yr0[64], v03 = yr0[96];
        float v10 = yr1[0], v11 = yr1[32], v12 = yr1[64], v13 = yr1[96];
        float v20 = yr2[0], v21 = yr2[32], v22 = yr2[64], v23 = yr2[96];
        float v30 = yr3[0], v31 = yr3[32], v32 = yr3[64], v33 = yr3[96];

        if (part == 0) {                     // degree count (exact; w-guarded adds below are 0 for tails)
            atomicAdd(&cnt[l0], 1);
            if (n > 1) atomicAdd(&cnt[l1], 1);
            if (n > 2) atomicAdd(&cnt[l2], 1);
            if (n > 3) atomicAdd(&cnt[l3], 1);
        }

        float* a0 = acc + l0 * D + part;
        float* a1 = acc + l1 * D + part;
        float* a2 = acc + l2 * D + part;
        float* a3 = acc + l3 * D + part;
        atomicAdd(a0 +  0, w0 * v00); atomicAdd(a0 + 32, w0 * v01);
        atomicAdd(a0 + 64, w0 * v02); atomicAdd(a0 + 96, w0 * v03);
        atomicAdd(a1 +  0, w1 * v10); atomicAdd(a1 + 32, w1 * v11);
        atomicAdd(a1 + 64, w1 * v12); atomicAdd(a1 + 96, w1 * v13);
        atomicAdd(a2 +  0, w2 * v20); atomicAdd(a2 + 32, w2 * v21);
        atomicAdd(a2 + 64, w2 * v22); atomicAdd(a2 + 96, w2 * v23);
        atomicAdd(a3 +  0, w3 * v30); atomicAdd(a3 + 32, w3 * v31);
        atomicAdd(a3 + 64, w3 * v32); atomicAdd(a3 + 96, w3 * v33);
    }
    __syncthreads();

    const float4* b4 = reinterpret_cast<const float4*>(b);
    f32x4* out4 = reinterpret_cast<f32x4*>(out);
    int nrows = N_NODES - node0; if (nrows > NPB) nrows = NPB;
    for (int r = g; r < nrows; r += 16) {
        int node = node0 + r;
        int dg = cnt[r];
        float inv = (dg > 0) ? (1.0f / (float)dg) : 0.0f;
        float4 bv = b4[part];
        const float* ar = acc + r * D + part * 4;
        f32x4 o;
        o.x = ar[0] * inv + bv.x;
        o.y = ar[1] * inv + bv.y;
        o.z = ar[2] * inv + bv.z;
        o.w = ar[3] * inv + bv.w;
        __builtin_nontemporal_store(o, out4 + node * (D / 4) + part);
    }
}

// ---------------------------------------------------------------------------
extern "C" void kernel_launch(void* const* d_in, const int* in_sizes, int n_in,
                              void* d_out, int out_size, void* d_ws, size_t ws_size,
                              hipStream_t stream) {
    const float* x   = (const float*)d_in[0];
    const int*   src = (const int*)d_in[1];
    const int*   dst = (const int*)d_in[2];
    const float* ew  = (const float*)d_in[3];
    const float* W   = (const float*)d_in[4];
    const float* b   = (const float*)d_in[5];
    float* out = (float*)d_out;

    char* ws = (char*)d_ws;
    float* y     = (float*)ws;                        ws += (size_t)N_NODES * D * 4;
    int*   ccnt  = (int*)ws;                          ws += (size_t)NBUCK * 4;
    int*   cbase = (int*)ws;                          ws += (size_t)(NBUCK + 4) * 4;
    int*   ccur  = (int*)ws;                          ws += (size_t)NBUCK * 4;
    u64*   pairs = (u64*)ws;

    hipMemsetAsync(ccnt, 0, (size_t)NBUCK * 4, stream);

    hist_kernel<<<HB, 256, 0, stream>>>(dst, ccnt);
    scan_kernel<<<1, NBUCK, 0, stream>>>(ccnt, cbase, ccur);
    scatterA_kernel<<<HB, 256, 0, stream>>>(src, dst, ew, ccur, pairs);
    gemm_xw_kernel<<<N_NODES / GEMM_ROWS, 256, 0, stream>>>(x, W, y);
    passB_kernel<<<NBUCK, 512, 0, stream>>>(cbase, pairs, y, b, out);
}

// Round 11
// 582.563 us; speedup vs baseline: 1.0332x; 1.0001x over previous
//
#include <hip/hip_runtime.h>

#define N_NODES 40000
#define N_EDGES 640000
#define D 128                  // D_IN == D_OUT == 128
#define GEMM_ROWS 32           // rows per gemm block (40000/32 = 1250 exact)
#define NBUCK 1024             // coarse dst-buckets
#define NPB   40               // nodes per bucket; 1000*40 = 40000 exact
#define HB    64               // histogram/scatter blocks
#define EPHB  (N_EDGES / HB)   // 10000 edges per block (exact)

typedef float f32x4 __attribute__((ext_vector_type(4)));
typedef unsigned long long u64;

// ---------------------------------------------------------------------------
// Workspace layout (16B-aligned):
//   y      : N_NODES*D f32   (x @ W)
//   ccnt   : NBUCK int       (bucket counts)  <- only thing memset to 0
//   cbase  : NBUCK+4 int     (bucket offsets, exclusive scan)
//   ccur   : NBUCK int       (bucket fill cursors)
//   pairs  : N_EDGES u64     (lo16=src, [16:23]=dstloc, hi32=bits(ew)), bucket-grouped
// Degree recovered inside passB (all edges of node v are in bucket v/NPB).
// ---------------------------------------------------------------------------

// K1: per-bucket histogram (LDS) only.
__global__ __launch_bounds__(256) void hist_kernel(const int* __restrict__ dst,
                                                   int* __restrict__ ccnt) {
    __shared__ int hist[NBUCK];
    const int tid = threadIdx.x;
    for (int i = tid; i < NBUCK; i += 256) hist[i] = 0;
    __syncthreads();
    const int base = blockIdx.x * EPHB;
    for (int i = tid; i < EPHB; i += 256)
        atomicAdd(&hist[dst[base + i] / NPB], 1);   // LDS int atomic (native)
    __syncthreads();
    for (int i = tid; i < NBUCK; i += 256) {
        int h = hist[i];
        if (h) atomicAdd(&ccnt[i], h);
    }
}

// K2: exclusive scan of ccnt[1024] -> cbase; init ccur = cbase.
__global__ __launch_bounds__(1024) void scan_kernel(const int* __restrict__ ccnt,
                                                    int* __restrict__ cbase,
                                                    int* __restrict__ ccur) {
    __shared__ int s[NBUCK];
    int t = threadIdx.x;
    int v = ccnt[t];
    s[t] = v;
    __syncthreads();
#pragma unroll
    for (int off = 1; off < NBUCK; off <<= 1) {
        int u = (t >= off) ? s[t - off] : 0;
        __syncthreads();
        s[t] += u;
        __syncthreads();
    }
    int excl = s[t] - v;
    cbase[t] = excl;
    ccur[t]  = excl;
    if (t == NBUCK - 1) cbase[NBUCK] = excl + v;   // == N_EDGES
}

// K3: bucket-grouped edge scatter with per-block dense reservations.
__global__ __launch_bounds__(256) void scatterA_kernel(const int* __restrict__ src,
                                                       const int* __restrict__ dst,
                                                       const float* __restrict__ ew,
                                                       int* __restrict__ ccur,
                                                       u64* __restrict__ pairs) {
    __shared__ int hbase[NBUCK];   // count, then block's reserved base
    __shared__ int lcur[NBUCK];    // local fill cursor
    const int tid = threadIdx.x;
    for (int i = tid; i < NBUCK; i += 256) hbase[i] = 0;
    __syncthreads();
    const int base = blockIdx.x * EPHB;
    for (int i = tid; i < EPHB; i += 256)
        atomicAdd(&hbase[dst[base + i] / NPB], 1);
    __syncthreads();
    for (int i = tid; i < NBUCK; i += 256) {
        int h = hbase[i];
        hbase[i] = h ? atomicAdd(&ccur[i], h) : 0;
        lcur[i] = 0;
    }
    __syncthreads();
    for (int i = tid; i < EPHB; i += 256) {
        int d = dst[base + i];
        int bk = d / NPB;
        int loc = d - bk * NPB;                       // < 40
        int pos = hbase[bk] + atomicAdd(&lcur[bk], 1);
        u64 pk = (u64)(unsigned int)(src[base + i] | (loc << 16))
               | ((u64)__float_as_uint(ew[base + i]) << 32);
        pairs[pos] = pk;                              // dense, L2-absorbed
    }
}

// K4: y = x @ W (fp32 vector GEMM; no fp32 MFMA on CDNA4).
// Block = 256 threads computes a 32-row x 128-col tile; W (64KB) + x tile
// (16KB) staged in LDS (REQUIRED: global-W version is latency-bound, R6).
__global__ __launch_bounds__(256) void gemm_xw_kernel(const float* __restrict__ x,
                                                      const float* __restrict__ W,
                                                      float* __restrict__ y) {
    __shared__ float Ws[D * D];             // 64 KB, [k][c] row-major
    __shared__ float xs[GEMM_ROWS * D];     // 16 KB
    const int tid = threadIdx.x;
    const int rowbase = blockIdx.x * GEMM_ROWS;

    float4* Ws4 = reinterpret_cast<float4*>(Ws);
    const float4* W4 = reinterpret_cast<const float4*>(W);
#pragma unroll
    for (int i = 0; i < 16; ++i)                  // 4096 float4 / 256 thr
        Ws4[tid + i * 256] = W4[tid + i * 256];

    float4* xs4 = reinterpret_cast<float4*>(xs);
    const float4* x4 = reinterpret_cast<const float4*>(x) + rowbase * (D / 4);
#pragma unroll
    for (int i = 0; i < GEMM_ROWS * (D / 4) / 256; ++i)   // 1024/256 = 4
        xs4[tid + i * 256] = x4[tid + i * 256];
    __syncthreads();

    const int lane = tid & 31;
    const int rp   = tid >> 5;                    // 0..7 -> rows 4rp..4rp+3
    const float* xr0 = xs + (rp * 4 + 0) * D;
    const float* xr1 = xs + (rp * 4 + 1) * D;
    const float* xr2 = xs + (rp * 4 + 2) * D;
    const float* xr3 = xs + (rp * 4 + 3) * D;

    float4 a0 = {0.f,0.f,0.f,0.f}, a1 = a0, a2 = a0, a3 = a0;
#pragma unroll 4
    for (int k = 0; k < D; ++k) {
        float4 wv = Ws4[k * (D / 4) + lane];      // ds_read_b128
        float x0 = xr0[k], x1 = xr1[k], x2 = xr2[k], x3 = xr3[k];
        a0.x += x0*wv.x; a0.y += x0*wv.y; a0.z += x0*wv.z; a0.w += x0*wv.w;
        a1.x += x1*wv.x; a1.y += x1*wv.y; a1.z += x1*wv.z; a1.w += x1*wv.w;
        a2.x += x2*wv.x; a2.y += x2*wv.y; a2.z += x2*wv.z; a2.w += x2*wv.w;
        a3.x += x3*wv.x; a3.y += x3*wv.y; a3.z += x3*wv.z; a3.w += x3*wv.w;
    }

    float4* y4 = reinterpret_cast<float4*>(y);
    int r0 = rowbase + rp * 4;
    y4[(r0 + 0) * (D / 4) + lane] = a0;
    y4[(r0 + 1) * (D / 4) + lane] = a1;
    y4[(r0 + 2) * (D / 4) + lane] = a2;
    y4[(r0 + 3) * (D / 4) + lane] = a3;
}

// K5: per-bucket accumulate. One block (512 thr, 16 groups) per bucket.
// LDS acc is SWIZZLED: node l, col c lives at l*128 + (c&3)*32 + (c>>2), so
// the 4 hardware ds_add_f32 per edge (one per float4 component) hit bank
// `part` for every lane -> conflict-free. y read as float4 (16B/lane).
// unsafeAtomicAdd => ds_add_f32 (plain f32 atomicAdd lowers to a CAS loop,
// which serialized under contention: R9/R10 identical 444us).
__global__ __launch_bounds__(512) void passB_kernel(const int* __restrict__ cbase,
                                                    const u64* __restrict__ pairs,
                                                    const float* __restrict__ y,
                                                    const float* __restrict__ b,
                                                    float* __restrict__ out) {
    __shared__ float acc[NPB * D];   // 20 KB, swizzled layout
    __shared__ int   cnt[NPB];
    const int bkt = blockIdx.x;
    const int node0 = bkt * NPB;
    if (node0 >= N_NODES) return;    // uniform per block
    const int tid  = threadIdx.x;
    const int part = tid & 31;
    const int g    = tid >> 5;       // 0..15

    for (int i = tid; i < NPB * D; i += 512) acc[i] = 0.f;
    if (tid < NPB) cnt[tid] = 0;
    __syncthreads();

    const float4* y4 = reinterpret_cast<const float4*>(y);
    const int eb = cbase[bkt], ee = cbase[bkt + 1];
    for (int e0 = eb + g * 4; e0 < ee; e0 += 64) {
        int n = ee - e0; if (n > 4) n = 4;
        u64 p0 = pairs[e0];
        u64 p1 = (n > 1) ? pairs[e0 + 1] : 0;
        u64 p2 = (n > 2) ? pairs[e0 + 2] : 0;
        u64 p3 = (n > 3) ? pairs[e0 + 3] : 0;

        int   s0 = (int)(p0 & 0xffffu), l0 = (int)((p0 >> 16) & 0xffu);
        int   s1 = (int)(p1 & 0xffffu), l1 = (int)((p1 >> 16) & 0xffu);
        int   s2 = (int)(p2 & 0xffffu), l2 = (int)((p2 >> 16) & 0xffu);
        int   s3 = (int)(p3 & 0xffffu), l3 = (int)((p3 >> 16) & 0xffu);
        float w0 = __uint_as_float((unsigned int)(p0 >> 32));
        float w1 = (n > 1) ? __uint_as_float((unsigned int)(p1 >> 32)) : 0.f;
        float w2 = (n > 2) ? __uint_as_float((unsigned int)(p2 >> 32)) : 0.f;
        float w3 = (n > 3) ? __uint_as_float((unsigned int)(p3 >> 32)) : 0.f;

        // 4 independent 16B loads in flight (cols 4*part .. 4*part+3)
        float4 v0 = y4[s0 * 32 + part];
        float4 v1 = y4[s1 * 32 + part];
        float4 v2 = y4[s2 * 32 + part];
        float4 v3 = y4[s3 * 32 + part];

        if (part == 0) {                     // exact degree count (int = native)
            atomicAdd(&cnt[l0], 1);
            if (n > 1) atomicAdd(&cnt[l1], 1);
            if (n > 2) atomicAdd(&cnt[l2], 1);
            if (n > 3) atomicAdd(&cnt[l3], 1);
        }

        // swizzled: col 4*part+j -> offset j*32 + part (bank = part, all j)
        float* a0 = acc + l0 * D + part;
        float* a1 = acc + l1 * D + part;
        float* a2 = acc + l2 * D + part;
        float* a3 = acc + l3 * D + part;
        unsafeAtomicAdd(a0 +  0, w0 * v0.x); unsafeAtomicAdd(a0 + 32, w0 * v0.y);
        unsafeAtomicAdd(a0 + 64, w0 * v0.z); unsafeAtomicAdd(a0 + 96, w0 * v0.w);
        unsafeAtomicAdd(a1 +  0, w1 * v1.x); unsafeAtomicAdd(a1 + 32, w1 * v1.y);
        unsafeAtomicAdd(a1 + 64, w1 * v1.z); unsafeAtomicAdd(a1 + 96, w1 * v1.w);
        unsafeAtomicAdd(a2 +  0, w2 * v2.x); unsafeAtomicAdd(a2 + 32, w2 * v2.y);
        unsafeAtomicAdd(a2 + 64, w2 * v2.z); unsafeAtomicAdd(a2 + 96, w2 * v2.w);
        unsafeAtomicAdd(a3 +  0, w3 * v3.x); unsafeAtomicAdd(a3 + 32, w3 * v3.y);
        unsafeAtomicAdd(a3 + 64, w3 * v3.z); unsafeAtomicAdd(a3 + 96, w3 * v3.w);
    }
    __syncthreads();

    const float4* b4 = reinterpret_cast<const float4*>(b);
    f32x4* out4 = reinterpret_cast<f32x4*>(out);
    int nrows = N_NODES - node0; if (nrows > NPB) nrows = NPB;
    for (int r = g; r < nrows; r += 16) {
        int node = node0 + r;
        int dg = cnt[r];
        float inv = (dg > 0) ? (1.0f / (float)dg) : 0.0f;
        float4 bv = b4[part];                 // cols 4*part..4*part+3
        const float* ar = acc + r * D + part; // un-swizzle: col 4p+j @ j*32+p
        f32x4 o;
        o.x = ar[ 0] * inv + bv.x;
        o.y = ar[32] * inv + bv.y;
        o.z = ar[64] * inv + bv.z;
        o.w = ar[96] * inv + bv.w;
        __builtin_nontemporal_store(o, out4 + node * (D / 4) + part);
    }
}

// ---------------------------------------------------------------------------
extern "C" void kernel_launch(void* const* d_in, const int* in_sizes, int n_in,
                              void* d_out, int out_size, void* d_ws, size_t ws_size,
                              hipStream_t stream) {
    const float* x   = (const float*)d_in[0];
    const int*   src = (const int*)d_in[1];
    const int*   dst = (const int*)d_in[2];
    const float* ew  = (const float*)d_in[3];
    const float* W   = (const float*)d_in[4];
    const float* b   = (const float*)d_in[5];
    float* out = (float*)d_out;

    char* ws = (char*)d_ws;
    float* y     = (float*)ws;                        ws += (size_t)N_NODES * D * 4;
    int*   ccnt  = (int*)ws;                          ws += (size_t)NBUCK * 4;
    int*   cbase = (int*)ws;                          ws += (size_t)(NBUCK + 4) * 4;
    int*   ccur  = (int*)ws;                          ws += (size_t)NBUCK * 4;
    u64*   pairs = (u64*)ws;

    hipMemsetAsync(ccnt, 0, (size_t)NBUCK * 4, stream);

    hist_kernel<<<HB, 256, 0, stream>>>(dst, ccnt);
    scan_kernel<<<1, NBUCK, 0, stream>>>(ccnt, cbase, ccur);
    scatterA_kernel<<<HB, 256, 0, stream>>>(src, dst, ew, ccur, pairs);
    gemm_xw_kernel<<<N_NODES / GEMM_ROWS, 256, 0, stream>>>(x, W, y);
    passB_kernel<<<NBUCK, 512, 0, stream>>>(cbase, pairs, y, b, out);
}